// Round 2
// baseline (401.591 us; speedup 1.0000x reference)
//
#include <hip/hip_runtime.h>
#include <hip/hip_bf16.h>
#include <stdint.h>

using bf16 = __hip_bfloat16;
typedef __attribute__((ext_vector_type(8))) short bf16x8;
typedef __attribute__((ext_vector_type(4))) float f32x4;

#define BATCHN 512

// ---------------- async global->LDS 16B helper ----------------
__device__ __forceinline__ void gload_lds16(const void* g, void* l) {
  __builtin_amdgcn_global_load_lds(
      (const __attribute__((address_space(1))) uint32_t*)g,
      (__attribute__((address_space(3))) uint32_t*)l, 16, 0, 0);
}

// ---------------- gating + leaf probs ----------------
__global__ void gate_kernel(const float* __restrict__ x, const float* __restrict__ gw,
                            const float* __restrict__ gb, float* __restrict__ lp) {
  __shared__ float xs[128];
  __shared__ float gs[32];
  const int b = blockIdx.x;
  const int t = threadIdx.x; // 0..63
  xs[t] = x[b*128 + t];
  xs[t + 64] = x[b*128 + 64 + t];
  __syncthreads();
  if (t < 31) {
    float acc = gb[t];
    #pragma unroll 8
    for (int k = 0; k < 128; ++k) acc += xs[k] * gw[k*31 + t];
    gs[t] = 1.f / (1.f + __expf(-acc));
  }
  __syncthreads();
  if (t < 32) {
    float prob = 1.f;
    #pragma unroll
    for (int d = 1; d <= 5; ++d) {
      int i = t >> (6 - d);
      int node = (1 << (d - 1)) - 1 + i;
      float gv = gs[node];
      prob *= ((t >> (5 - d)) & 1) ? (1.f - gv) : gv;
    }
    lp[b*32 + t] = prob;
  }
}

// ---------------- mixture: out0 = lp @ z.T, written NHWC bf16 into x1 halo ----------------
__global__ void mixture_kernel(const float* __restrict__ z, const float* __restrict__ lp,
                               bf16* __restrict__ x1) {
  __shared__ float lps[64 * 32];
  const int s = blockIdx.x;          // h*8+w
  const int h = s >> 3, w = s & 7;
  const int b0 = blockIdx.y * 64;
  const int t = threadIdx.x;
  const int c = t & 127;
  const int half = t >> 7;
  float4 zr[8];
  const float4* zp = (const float4*)(z + (size_t)(c * 64 + s) * 32);
  #pragma unroll
  for (int i = 0; i < 8; ++i) zr[i] = zp[i];
  #pragma unroll
  for (int i = 0; i < 8; ++i) lps[t + 256 * i] = lp[b0 * 32 + t + 256 * i];
  __syncthreads();
  for (int bs = 0; bs < 32; ++bs) {
    int bl = half * 32 + bs;
    const float4* lr = (const float4*)(lps + bl * 32);
    float acc = 0.f;
    #pragma unroll
    for (int i = 0; i < 8; ++i) {
      float4 l4 = lr[i];
      acc += zr[i].x * l4.x + zr[i].y * l4.y + zr[i].z * l4.z + zr[i].w * l4.w;
    }
    int b = b0 + bl;
    x1[((size_t)(b * 10 + h + 1) * 10 + (w + 1)) * 128 + c] = __float2bfloat16(acc);
  }
}

// ---------------- zero the 1-px halo border of [512][H+2][W+2][C] bf16 ----------------
__global__ void zero_halo(bf16* __restrict__ buf, int H, int W, int C) {
  int idx = blockIdx.x * 256 + threadIdx.x;
  int nvec = C >> 3;
  int P = 2 * (W + 2) + 2 * H;
  int total = BATCHN * P * nvec;
  if (idx >= total) return;
  int cv = idx % nvec;
  int p = (idx / nvec) % P;
  int b = idx / (nvec * P);
  int row, col;
  if (p < W + 2) { row = 0; col = p; }
  else if (p < 2 * (W + 2)) { row = H + 1; col = p - (W + 2); }
  else { int q = p - 2 * (W + 2); row = 1 + (q >> 1); col = (q & 1) ? (W + 1) : 0; }
  float4 z4 = {0.f, 0.f, 0.f, 0.f};
  *(float4*)(buf + ((size_t)(b * (H + 2) + row) * (W + 2) + col) * C + cv * 8) = z4;
}

// ---------------- weight prep: w[ic][ocr][4][4] fp32 -> wt[parity][ocp][tap][ic] bf16 ----------------
__global__ void wprep_kernel(const float* __restrict__ w, bf16* __restrict__ wt,
                             int IC, int OCr, int OCp) {
  int idx = blockIdx.x * 256 + threadIdx.x;
  int total = 4 * OCp * 4 * IC;
  if (idx >= total) return;
  int ic = idx % IC;
  int tap = (idx / IC) & 3;
  int oc = (idx / (4 * IC)) % OCp;
  int p = idx / (4 * IC * OCp);
  int dy = tap >> 1, dx = tap & 1;
  int py = p >> 1, px = p & 1;
  const int ktab[2][2] = {{1, 3}, {2, 0}};
  int ky = ktab[py][dy], kx = ktab[px][dx];
  float v = 0.f;
  if (oc < OCr) v = w[((ic * OCr + oc) * 4 + ky) * 4 + kx];
  wt[idx] = __float2bfloat16(v);
}

// ---------------- transposed-conv as per-parity implicit GEMM (bf16 MFMA) ----------------
// parity folded into blockIdx.x low 2 bits (siblings co-resident -> L2/L3 reuse of xin).
// A/B global addresses hoisted: per-lane base pointers computed once; per K-step only a
// wave-uniform tap delta + ic offset is added (tap loop compile-time unrolled).
template<int IC, int OCp, int OCr, int IH, int IW, int BM, int BN, int WM, int WN, bool RELU, bool FINAL>
__global__ __launch_bounds__(256, 2)
void convt_mfma(const bf16* __restrict__ xin, const bf16* __restrict__ wt,
                const float* __restrict__ bias, bf16* __restrict__ xout,
                float* __restrict__ fout) {
  constexpr int BK = 32;
  constexpr int K = 4 * IC;
  constexpr int HS = IH * IW;
  constexpr int IH2 = IH + 2, IW2 = IW + 2;
  constexpr int OH2 = 2 * IH + 2, OW2 = 2 * IW + 2;
  constexpr int MI = WM / 16, NI = WN / 16;
  constexpr int WAVES_N = BN / WN;
  constexpr int AS = BM / 64;            // A staging insts per wave
  constexpr int BS = (BN / 16 + 3) / 4;  // B staging insts per wave (upper bound)
  __shared__ bf16 Alds[BM * BK];
  __shared__ bf16 Blds[BN * BK];
  const int p = blockIdx.x & 3, py = p >> 1, px = p & 1;
  const int mb = blockIdx.x >> 2;
  const int tid = threadIdx.x;
  const int wave = tid >> 6, lane = tid & 63;
  const int wn = wave % WAVES_N, wm = wave / WAVES_N;
  const int m0 = mb * BM, n0 = blockIdx.y * BN;

  f32x4 acc[MI][NI];
  #pragma unroll
  for (int i = 0; i < MI; ++i)
    #pragma unroll
    for (int j = 0; j < NI; ++j)
      acc[i][j] = (f32x4){0.f, 0.f, 0.f, 0.f};

  // per-lane A base pointers (tap 0), computed once
  const bf16* baseA[AS];
  bf16* ldsA[AS];
  #pragma unroll
  for (int s = 0; s < AS; ++s) {
    const int si = wave + 4 * s;
    const int rl = si * 16 + (lane >> 2);
    const int m = m0 + rl;
    const int b = m / HS;
    const int rem = m % HS;
    const int iy = rem / IW + 1;
    const int ix = (rem & (IW - 1)) + 1;
    baseA[s] = xin + (((size_t)b * IH2 + iy) * IW2 + ix) * IC + (lane & 3) * 8;
    ldsA[s] = Alds + si * 16 * BK;
  }
  // per-lane B base pointers
  const bf16* baseB[BS];
  bf16* ldsB[BS];
  int nB = 0;
  for (int s = wave; s < BN / 16; s += 4, ++nB) {
    const int oc = n0 + s * 16 + (lane >> 2);
    baseB[nB] = wt + ((size_t)(p * OCp + oc)) * K + (lane & 3) * 8;
    ldsB[nB] = Blds + s * 16 * BK;
  }

  // wave-uniform tap deltas (elements)
  const int oy1 = py ? 1 : -1;
  const int ox1 = px ? 1 : -1;
  const int dA[4] = {0, ox1 * IC, oy1 * IW2 * IC, (oy1 * IW2 + ox1) * IC};

  #pragma unroll
  for (int tap = 0; tap < 4; ++tap) {
    #pragma unroll
    for (int kk = 0; kk < IC; kk += BK) {
      __syncthreads();
      #pragma unroll
      for (int s = 0; s < AS; ++s)
        gload_lds16(baseA[s] + dA[tap] + kk, ldsA[s]);
      for (int s = 0; s < nB; ++s)
        gload_lds16(baseB[s] + tap * IC + kk, ldsB[s]);
      __syncthreads();
      bf16x8 af[MI], bfr[NI];
      #pragma unroll
      for (int i = 0; i < MI; ++i)
        af[i] = *(const bf16x8*)(Alds + (wm * WM + i * 16 + (lane & 15)) * BK + (lane >> 4) * 8);
      #pragma unroll
      for (int j = 0; j < NI; ++j)
        bfr[j] = *(const bf16x8*)(Blds + (wn * WN + j * 16 + (lane & 15)) * BK + (lane >> 4) * 8);
      #pragma unroll
      for (int i = 0; i < MI; ++i)
        #pragma unroll
        for (int j = 0; j < NI; ++j)
          acc[i][j] = __builtin_amdgcn_mfma_f32_16x16x32_bf16(af[i], bfr[j], acc[i][j], 0, 0, 0);
    }
  }

  // epilogue: C/D layout col = lane&15, row = (lane>>4)*4 + r
  #pragma unroll
  for (int j = 0; j < NI; ++j) {
    const int oc = n0 + wn * WN + j * 16 + (lane & 15);
    if (oc >= OCr) continue;  // padded cols (conv3)
    const float bv = bias[oc];
    #pragma unroll
    for (int i = 0; i < MI; ++i) {
      #pragma unroll
      for (int r = 0; r < 4; ++r) {
        const int ml = wm * WM + i * 16 + (lane >> 4) * 4 + r;
        const int m = m0 + ml;
        const int b = m / HS;
        const int rem = m % HS;
        const int oy = 2 * (rem / IW) + py;
        const int ox = 2 * (rem & (IW - 1)) + px;
        float v = acc[i][j][r] + bv;
        if (RELU) v = fmaxf(v, 0.f);
        if (FINAL) {
          fout[((size_t)(b * 3 + oc) * 64 + oy) * 64 + ox] = v;
        } else {
          xout[(((size_t)b * OH2 + oy + 1) * OW2 + ox + 1) * OCp + oc] = __float2bfloat16(v);
        }
      }
    }
  }
}

// ---------------- launch ----------------
extern "C" void kernel_launch(void* const* d_in, const int* in_sizes, int n_in,
                              void* d_out, int out_size, void* d_ws, size_t ws_size,
                              hipStream_t stream) {
  const float* x  = (const float*)d_in[0];
  const float* gw = (const float*)d_in[1];
  const float* gb = (const float*)d_in[2];
  const float* z  = (const float*)d_in[3];
  const float* w1 = (const float*)d_in[4];
  const float* b1 = (const float*)d_in[5];
  const float* w2 = (const float*)d_in[6];
  const float* b2 = (const float*)d_in[7];
  const float* w3 = (const float*)d_in[8];
  const float* b3 = (const float*)d_in[9];
  float* out = (float*)d_out;

  char* w = (char*)d_ws;
  float* lp  = (float*)(w);
  bf16* x1  = (bf16*)(w + 65536);
  bf16* x2  = (bf16*)(w + 13172736);
  bf16* x3  = (bf16*)(w + 55640064);
  bf16* wt1 = (bf16*)(w + 131399680);
  bf16* wt2 = (bf16*)(w + 131923968);
  bf16* wt3 = (bf16*)(w + 132186112);

  // halo zeroing (borders only)
  zero_halo<<<(512*36*16 + 255) / 256, 256, 0, stream>>>(x1, 8, 8, 128);
  zero_halo<<<(512*68*16 + 255) / 256, 256, 0, stream>>>(x2, 16, 16, 128);
  zero_halo<<<(512*132*8 + 255) / 256, 256, 0, stream>>>(x3, 32, 32, 64);

  // gating -> leaf probabilities
  gate_kernel<<<512, 64, 0, stream>>>(x, gw, gb, lp);

  // weight transforms (fp32 -> per-parity bf16)
  wprep_kernel<<<(4*128*4*128 + 255) / 256, 256, 0, stream>>>(w1, wt1, 128, 128, 128);
  wprep_kernel<<<(4*64*4*128 + 255) / 256, 256, 0, stream>>>(w2, wt2, 128, 64, 64);
  wprep_kernel<<<(4*16*4*64 + 255) / 256, 256, 0, stream>>>(w3, wt3, 64, 3, 16);

  // mixture -> x1 interior (NHWC bf16)
  mixture_kernel<<<dim3(64, 8), 256, 0, stream>>>(z, lp, x1);

  // conv1: 128->128, 8x8 -> 16x16, relu.  M/parity = 32768, 256 m-blocks x4 parities
  convt_mfma<128,128,128, 8, 8, 128,128, 64,64, true,false>
      <<<dim3(256*4, 1, 1), 256, 0, stream>>>(x1, wt1, b1, x2, nullptr);
  // conv2: 128->64, 16x16 -> 32x32, relu. M/parity = 131072, 1024 m-blocks x4
  convt_mfma<128, 64, 64,16,16, 128, 64, 64,32, true,false>
      <<<dim3(1024*4, 1, 1), 256, 0, stream>>>(x2, wt2, b2, x3, nullptr);
  // conv3: 64->3 (pad 16), 32x32 -> 64x64, final fp32 NCHW. M/parity = 524288, BM=256 -> 2048 x4
  convt_mfma< 64, 16,  3,32,32, 256, 16, 64,16, false,true>
      <<<dim3(2048*4, 1, 1), 256, 0, stream>>>(x3, wt3, b3, nullptr, out);
}

// Round 4
// 366.624 us; speedup vs baseline: 1.0954x; 1.0954x over previous
//
#include <hip/hip_runtime.h>
#include <hip/hip_bf16.h>
#include <stdint.h>

using bf16 = __hip_bfloat16;
typedef __attribute__((ext_vector_type(8))) short bf16x8;
typedef __attribute__((ext_vector_type(4))) float f32x4;

#define BATCHN 512

// ---------------- gating + leaf probs ----------------
__global__ void gate_kernel(const float* __restrict__ x, const float* __restrict__ gw,
                            const float* __restrict__ gb, float* __restrict__ lp) {
  __shared__ float xs[128];
  __shared__ float gs[32];
  const int b = blockIdx.x;
  const int t = threadIdx.x; // 0..63
  xs[t] = x[b*128 + t];
  xs[t + 64] = x[b*128 + 64 + t];
  __syncthreads();
  if (t < 31) {
    float acc = gb[t];
    #pragma unroll 8
    for (int k = 0; k < 128; ++k) acc += xs[k] * gw[k*31 + t];
    gs[t] = 1.f / (1.f + __expf(-acc));
  }
  __syncthreads();
  if (t < 32) {
    float prob = 1.f;
    #pragma unroll
    for (int d = 1; d <= 5; ++d) {
      int i = t >> (6 - d);
      int node = (1 << (d - 1)) - 1 + i;
      float gv = gs[node];
      prob *= ((t >> (5 - d)) & 1) ? (1.f - gv) : gv;
    }
    lp[b*32 + t] = prob;
  }
}

// ---------------- mixture: out0 = lp @ z.T, written NHWC bf16 into x1 halo ----------------
__global__ void mixture_kernel(const float* __restrict__ z, const float* __restrict__ lp,
                               bf16* __restrict__ x1) {
  __shared__ float lps[64 * 32];
  const int s = blockIdx.x;          // h*8+w
  const int h = s >> 3, w = s & 7;
  const int b0 = blockIdx.y * 64;
  const int t = threadIdx.x;
  const int c = t & 127;
  const int half = t >> 7;
  float4 zr[8];
  const float4* zp = (const float4*)(z + (size_t)(c * 64 + s) * 32);
  #pragma unroll
  for (int i = 0; i < 8; ++i) zr[i] = zp[i];
  #pragma unroll
  for (int i = 0; i < 8; ++i) lps[t + 256 * i] = lp[b0 * 32 + t + 256 * i];
  __syncthreads();
  for (int bs = 0; bs < 32; ++bs) {
    int bl = half * 32 + bs;
    const float4* lr = (const float4*)(lps + bl * 32);
    float acc = 0.f;
    #pragma unroll
    for (int i = 0; i < 8; ++i) {
      float4 l4 = lr[i];
      acc += zr[i].x * l4.x + zr[i].y * l4.y + zr[i].z * l4.z + zr[i].w * l4.w;
    }
    int b = b0 + bl;
    x1[((size_t)(b * 10 + h + 1) * 10 + (w + 1)) * 128 + c] = __float2bfloat16(acc);
  }
}

// ---------------- zero the 1-px halo border of [512][H+2][W+2][C] bf16 ----------------
__global__ void zero_halo(bf16* __restrict__ buf, int H, int W, int C) {
  int idx = blockIdx.x * 256 + threadIdx.x;
  int nvec = C >> 3;
  int P = 2 * (W + 2) + 2 * H;
  int total = BATCHN * P * nvec;
  if (idx >= total) return;
  int cv = idx % nvec;
  int p = (idx / nvec) % P;
  int b = idx / (nvec * P);
  int row, col;
  if (p < W + 2) { row = 0; col = p; }
  else if (p < 2 * (W + 2)) { row = H + 1; col = p - (W + 2); }
  else { int q = p - 2 * (W + 2); row = 1 + (q >> 1); col = (q & 1) ? (W + 1) : 0; }
  float4 z4 = {0.f, 0.f, 0.f, 0.f};
  *(float4*)(buf + ((size_t)(b * (H + 2) + row) * (W + 2) + col) * C + cv * 8) = z4;
}

// ---------------- weight prep: w[ic][ocr][4][4] fp32 -> wt[parity][ocp][tap][ic] bf16 ----------------
__global__ void wprep_kernel(const float* __restrict__ w, bf16* __restrict__ wt,
                             int IC, int OCr, int OCp) {
  int idx = blockIdx.x * 256 + threadIdx.x;
  int total = 4 * OCp * 4 * IC;
  if (idx >= total) return;
  int ic = idx % IC;
  int tap = (idx / IC) & 3;
  int oc = (idx / (4 * IC)) % OCp;
  int p = idx / (4 * IC * OCp);
  int dy = tap >> 1, dx = tap & 1;
  int py = p >> 1, px = p & 1;
  const int ktab[2][2] = {{1, 3}, {2, 0}};
  int ky = ktab[py][dy], kx = ktab[px][dx];
  float v = 0.f;
  if (oc < OCr) v = w[((ic * OCr + oc) * 4 + ky) * 4 + kx];
  wt[idx] = __float2bfloat16(v);
}

// ---------------- parity-fused transposed conv ----------------
// Stage spatial tile [ROWS+2][IW2][IC] (padded pixels) into LDS ONCE through VGPRs;
// compute all 4 parity outputs from the resident tile. B fragments read directly
// from global (wt is L2-resident). One __syncthreads per block; no K-loop barriers.
// A-fragment dedup: 9 distinct spatial shifts serve the 16 (tap,parity) pairs.
template<int IC, int OCp, int OCr, int IH, int IW, int ROWS, int BN,
         int WAVES_M, int WAVES_N, int MI, int NI, bool RELU, bool FINAL>
__global__ __launch_bounds__(256, 2)
void convt_fused(const bf16* __restrict__ xin, const bf16* __restrict__ wt,
                 const float* __restrict__ bias, bf16* __restrict__ xout,
                 float* __restrict__ fout) {
  constexpr int K = 4 * IC;
  constexpr int BK = 32;
  constexpr int NC = IC / BK;
  constexpr int IH2 = IH + 2, IW2 = IW + 2;
  constexpr int OH2 = 2 * IH + 2, OW2 = 2 * IW + 2;
  constexpr int PIX = IC + 8;          // +16B pad per pixel -> 2-way (free) LDS banks
  constexpr int BPI = IH / ROWS;
  constexpr int WN = NI * 16;
  constexpr int LIW = (IW == 8 ? 3 : (IW == 16 ? 4 : 5));
  constexpr int GROUPS = (ROWS + 2) * IW2 * IC / 8;
  __shared__ bf16 Alds[(ROWS + 2) * IW2 * PIX];

  const int tid = threadIdx.x;
  const int wave = tid >> 6, lane = tid & 63;
  const int q = lane >> 4, li = lane & 15;
  const int wm = wave / WAVES_N, wn = wave % WAVES_N;
  const int img = blockIdx.x / BPI;
  const int tb = blockIdx.x % BPI;
  const int n0 = blockIdx.y * BN;

  // ---- stage A tile (contiguous global span incl. halo rows) ----
  const bf16* src = xin + ((size_t)img * IH2 + tb * ROWS) * IW2 * IC;
  for (int g = tid; g < GROUPS; g += 256) {
    const int pix = g / (IC / 8);
    const int r8 = g % (IC / 8);
    const float4 v = *(const float4*)(src + (size_t)g * 8);
    *(float4*)(&Alds[pix * PIX + r8 * 8]) = v;
  }
  __syncthreads();

  f32x4 acc[4][MI][NI];
  #pragma unroll
  for (int p = 0; p < 4; ++p)
    #pragma unroll
    for (int mi = 0; mi < MI; ++mi)
      #pragma unroll
      for (int nj = 0; nj < NI; ++nj)
        acc[p][mi][nj] = (f32x4){0.f, 0.f, 0.f, 0.f};

  // per-mi A LDS pointers (lane li = m-row)
  const bf16* pA[MI];
  #pragma unroll
  for (int mi = 0; mi < MI; ++mi) {
    const int pix = (wm * MI + mi) * 16 + li;
    const int y = pix >> LIW, x = pix & (IW - 1);
    pA[mi] = Alds + ((y + 1) * IW2 + (x + 1)) * PIX + q * 8;
  }
  // per-(p,nj) B global pointers (lane li = oc)
  const bf16* pB[4][NI];
  #pragma unroll
  for (int p = 0; p < 4; ++p)
    #pragma unroll
    for (int nj = 0; nj < NI; ++nj)
      pB[p][nj] = wt + ((size_t)(p * OCp + n0 + wn * WN + nj * 16 + li)) * K + q * 8;

  // 9 shift-variants covering the 16 (tap,parity) pairs
  const int TAPA[9] = {0, 1, 1, 2, 2, 3, 3, 3, 3};
  const int DYA[9]  = {0, 0, 0,-1, 1,-1,-1, 1, 1};
  const int DXA[9]  = {0,-1, 1, 0, 0,-1, 1,-1, 1};
  const int MSK[9]  = {0xF,0x5,0xA,0x3,0xC,0x1,0x2,0x4,0x8};

  #pragma unroll
  for (int e = 0; e < 9; ++e) {
    const int tap = TAPA[e];
    const int sh = (DYA[e] * IW2 + DXA[e]) * PIX;
    const int msk = MSK[e];
    #pragma unroll
    for (int c = 0; c < NC; ++c) {
      bf16x8 bfr[4][NI];
      #pragma unroll
      for (int p = 0; p < 4; ++p)
        if (msk & (1 << p))
          #pragma unroll
          for (int nj = 0; nj < NI; ++nj)
            bfr[p][nj] = *(const bf16x8*)(pB[p][nj] + tap * IC + c * BK);
      #pragma unroll
      for (int mi = 0; mi < MI; ++mi) {
        const bf16x8 a = *(const bf16x8*)(pA[mi] + sh + c * BK);
        #pragma unroll
        for (int p = 0; p < 4; ++p)
          if (msk & (1 << p))
            #pragma unroll
            for (int nj = 0; nj < NI; ++nj)
              acc[p][mi][nj] = __builtin_amdgcn_mfma_f32_16x16x32_bf16(a, bfr[p][nj], acc[p][mi][nj], 0, 0, 0);
      }
    }
  }

  // ---- epilogue: C/D row = q*4+r (m), col = li (oc) ----
  // NOTE: y is tile-local; output row needs the tile offset tb*ROWS (round-3 bug).
  if (!FINAL) {
    #pragma unroll
    for (int p = 0; p < 4; ++p) {
      const int py = p >> 1, px = p & 1;
      #pragma unroll
      for (int nj = 0; nj < NI; ++nj) {
        const int oc = n0 + wn * WN + nj * 16 + li;
        const float bv = bias[oc];
        #pragma unroll
        for (int mi = 0; mi < MI; ++mi) {
          #pragma unroll
          for (int r = 0; r < 4; ++r) {
            const int pix = (wm * MI + mi) * 16 + q * 4 + r;
            const int y = tb * ROWS + (pix >> LIW), x = pix & (IW - 1);
            float v = acc[p][mi][nj][r] + bv;
            if (RELU) v = fmaxf(v, 0.f);
            xout[(((size_t)img * OH2 + 2 * y + py + 1) * OW2 + 2 * x + px + 1) * OCp + oc] =
                __float2bfloat16(v);
          }
        }
      }
    }
  } else {
    const int oc = li;  // NI==1, wn==0 for FINAL config
    if (oc < OCr) {
      const float bv = bias[oc];
      #pragma unroll
      for (int py = 0; py < 2; ++py)
        #pragma unroll
        for (int mi = 0; mi < MI; ++mi)
          #pragma unroll
          for (int r = 0; r < 4; ++r) {
            const int pix = (wm * MI + mi) * 16 + q * 4 + r;
            const int y = tb * ROWS + (pix >> LIW), x = pix & (IW - 1);
            float2 v2;
            v2.x = acc[py * 2 + 0][mi][0][r] + bv;
            v2.y = acc[py * 2 + 1][mi][0][r] + bv;
            *(float2*)(&fout[(((size_t)img * 3 + oc) * 64 + 2 * y + py) * 64 + 2 * x]) = v2;
          }
    }
  }
}

// ---------------- launch ----------------
extern "C" void kernel_launch(void* const* d_in, const int* in_sizes, int n_in,
                              void* d_out, int out_size, void* d_ws, size_t ws_size,
                              hipStream_t stream) {
  const float* x  = (const float*)d_in[0];
  const float* gw = (const float*)d_in[1];
  const float* gb = (const float*)d_in[2];
  const float* z  = (const float*)d_in[3];
  const float* w1 = (const float*)d_in[4];
  const float* b1 = (const float*)d_in[5];
  const float* w2 = (const float*)d_in[6];
  const float* b2 = (const float*)d_in[7];
  const float* w3 = (const float*)d_in[8];
  const float* b3 = (const float*)d_in[9];
  float* out = (float*)d_out;

  char* w = (char*)d_ws;
  float* lp  = (float*)(w);
  bf16* x1  = (bf16*)(w + 65536);
  bf16* x2  = (bf16*)(w + 13172736);
  bf16* x3  = (bf16*)(w + 55640064);
  bf16* wt1 = (bf16*)(w + 131399680);
  bf16* wt2 = (bf16*)(w + 131923968);
  bf16* wt3 = (bf16*)(w + 132186112);

  // halo zeroing (borders only)
  zero_halo<<<(512*36*16 + 255) / 256, 256, 0, stream>>>(x1, 8, 8, 128);
  zero_halo<<<(512*68*16 + 255) / 256, 256, 0, stream>>>(x2, 16, 16, 128);
  zero_halo<<<(512*132*8 + 255) / 256, 256, 0, stream>>>(x3, 32, 32, 64);

  // gating -> leaf probabilities
  gate_kernel<<<512, 64, 0, stream>>>(x, gw, gb, lp);

  // weight transforms (fp32 -> per-parity bf16)
  wprep_kernel<<<(4*128*4*128 + 255) / 256, 256, 0, stream>>>(w1, wt1, 128, 128, 128);
  wprep_kernel<<<(4*64*4*128 + 255) / 256, 256, 0, stream>>>(w2, wt2, 128, 64, 64);
  wprep_kernel<<<(4*16*4*64 + 255) / 256, 256, 0, stream>>>(w3, wt3, 64, 3, 16);

  // mixture -> x1 interior (NHWC bf16)
  mixture_kernel<<<dim3(64, 8), 256, 0, stream>>>(z, lp, x1);

  // conv1: 128->128, 8x8 -> 16x16, relu. 1 tile/image, N split in 2.
  convt_fused<128,128,128, 8, 8, 8, 64, 2,2, 2,2, true,false>
      <<<dim3(512, 2), 256, 0, stream>>>(x1, wt1, b1, x2, nullptr);
  // conv2: 128->64, 16x16 -> 32x32, relu. 4 tiles/image (4 rows each).
  convt_fused<128, 64, 64,16,16, 4, 64, 2,2, 2,2, true,false>
      <<<dim3(2048, 1), 256, 0, stream>>>(x2, wt2, b2, x3, nullptr);
  // conv3: 64->3(pad16), 32x32 -> 64x64, fp32 NCHW out, float2 px-pair stores.
  convt_fused< 64, 16,  3,32,32, 8, 16, 4,1, 4,1, false,true>
      <<<dim3(2048, 1), 256, 0, stream>>>(x3, wt3, b3, nullptr, out);
}

// Round 5
// 240.030 us; speedup vs baseline: 1.6731x; 1.5274x over previous
//
#include <hip/hip_runtime.h>
#include <hip/hip_bf16.h>
#include <stdint.h>

using bf16 = __hip_bfloat16;
typedef __attribute__((ext_vector_type(8))) short bf16x8;
typedef __attribute__((ext_vector_type(4))) float f32x4;

#define BATCHN 512

// ---------------- async global->LDS 16B helper ----------------
__device__ __forceinline__ void gload_lds16(const void* g, void* l) {
  __builtin_amdgcn_global_load_lds(
      (const __attribute__((address_space(1))) uint32_t*)g,
      (__attribute__((address_space(3))) uint32_t*)l, 16, 0, 0);
}

// ---------------- gating + leaf probs ----------------
__global__ void gate_kernel(const float* __restrict__ x, const float* __restrict__ gw,
                            const float* __restrict__ gb, float* __restrict__ lp) {
  __shared__ float xs[128];
  __shared__ float gs[32];
  const int b = blockIdx.x;
  const int t = threadIdx.x; // 0..63
  xs[t] = x[b*128 + t];
  xs[t + 64] = x[b*128 + 64 + t];
  __syncthreads();
  if (t < 31) {
    float acc = gb[t];
    #pragma unroll 8
    for (int k = 0; k < 128; ++k) acc += xs[k] * gw[k*31 + t];
    gs[t] = 1.f / (1.f + __expf(-acc));
  }
  __syncthreads();
  if (t < 32) {
    float prob = 1.f;
    #pragma unroll
    for (int d = 1; d <= 5; ++d) {
      int i = t >> (6 - d);
      int node = (1 << (d - 1)) - 1 + i;
      float gv = gs[node];
      prob *= ((t >> (5 - d)) & 1) ? (1.f - gv) : gv;
    }
    lp[b*32 + t] = prob;
  }
}

// ---------------- mixture: out0 = lp @ z.T, written NHWC bf16 into x1 halo ----------------
__global__ void mixture_kernel(const float* __restrict__ z, const float* __restrict__ lp,
                               bf16* __restrict__ x1) {
  __shared__ float lps[64 * 32];
  const int s = blockIdx.x;          // h*8+w
  const int h = s >> 3, w = s & 7;
  const int b0 = blockIdx.y * 64;
  const int t = threadIdx.x;
  const int c = t & 127;
  const int half = t >> 7;
  float4 zr[8];
  const float4* zp = (const float4*)(z + (size_t)(c * 64 + s) * 32);
  #pragma unroll
  for (int i = 0; i < 8; ++i) zr[i] = zp[i];
  #pragma unroll
  for (int i = 0; i < 8; ++i) lps[t + 256 * i] = lp[b0 * 32 + t + 256 * i];
  __syncthreads();
  for (int bs = 0; bs < 32; ++bs) {
    int bl = half * 32 + bs;
    const float4* lr = (const float4*)(lps + bl * 32);
    float acc = 0.f;
    #pragma unroll
    for (int i = 0; i < 8; ++i) {
      float4 l4 = lr[i];
      acc += zr[i].x * l4.x + zr[i].y * l4.y + zr[i].z * l4.z + zr[i].w * l4.w;
    }
    int b = b0 + bl;
    x1[((size_t)(b * 10 + h + 1) * 10 + (w + 1)) * 128 + c] = __float2bfloat16(acc);
  }
}

// ---------------- zero the 1-px halo border of [512][H+2][W+2][C] bf16 ----------------
__global__ void zero_halo(bf16* __restrict__ buf, int H, int W, int C) {
  int idx = blockIdx.x * 256 + threadIdx.x;
  int nvec = C >> 3;
  int P = 2 * (W + 2) + 2 * H;
  int total = BATCHN * P * nvec;
  if (idx >= total) return;
  int cv = idx % nvec;
  int p = (idx / nvec) % P;
  int b = idx / (nvec * P);
  int row, col;
  if (p < W + 2) { row = 0; col = p; }
  else if (p < 2 * (W + 2)) { row = H + 1; col = p - (W + 2); }
  else { int q = p - 2 * (W + 2); row = 1 + (q >> 1); col = (q & 1) ? (W + 1) : 0; }
  float4 z4 = {0.f, 0.f, 0.f, 0.f};
  *(float4*)(buf + ((size_t)(b * (H + 2) + row) * (W + 2) + col) * C + cv * 8) = z4;
}

// ---------------- weight prep ----------------
// New layout = the exact per-chunk LDS image (so global_load_lds stages it
// contiguously): gB[chunk=(p*4+tap)][c][q][oc(OCp)][e=0..7], ic = c*32+q*8+e.
__global__ void wprep_kernel(const float* __restrict__ w, bf16* __restrict__ wt,
                             int IC, int OCr, int OCp) {
  int idx = blockIdx.x * 256 + threadIdx.x;
  int NC = IC / 32;
  int total = 16 * OCp * IC;
  if (idx >= total) return;
  int e = idx & 7;
  int t = idx >> 3;
  int oc = t % OCp; t /= OCp;
  int q = t & 3; t >>= 2;
  int c = t % NC; t /= NC;
  int tap = t & 3, p = t >> 2;
  int ic = c * 32 + q * 8 + e;
  int dy = tap >> 1, dx = tap & 1;
  int py = p >> 1, px = p & 1;
  const int ktab[2][2] = {{1, 3}, {2, 0}};
  int ky = ktab[py][dy], kx = ktab[px][dx];
  float v = 0.f;
  if (oc < OCr) v = w[((ic * OCr + oc) * 4 + ky) * 4 + kx];
  wt[idx] = __float2bfloat16(v);
}

// ---------------- pipelined parity-fused transposed conv ----------------
// A: spatial tile staged ONCE into LDS, k-interleaved [plane=c*4+q][pix][8].
// B: 16 chunks (p,tap), double-buffered in LDS, filled by async global_load_lds
//    (prefetch chunk+1 while computing chunk). wt is pre-laid-out per chunk.
template<int IC, int OCp, int OCr, int IH, int IW, int ROWS, int BN,
         int WAVES_M, int WAVES_N, int MI, int NI, bool RELU, bool FINAL>
__global__ __launch_bounds__(256, 2)
void convt_pipe(const bf16* __restrict__ xin, const bf16* __restrict__ wt,
                const float* __restrict__ bias, bf16* __restrict__ xout,
                float* __restrict__ fout) {
  constexpr int NC = IC / 32;
  constexpr int PLANES = NC * 4;
  constexpr int IH2 = IH + 2, IW2 = IW + 2;
  constexpr int OH2 = 2 * IH + 2, OW2 = 2 * IW + 2;
  constexpr int NPIX = (ROWS + 2) * IW2;
  constexpr int CHUNK = PLANES * BN * 8;   // elems per B chunk
  constexpr int NP = CHUNK / 512;          // 1024-B pieces per chunk
  constexpr int BPI = IH / ROWS;
  constexpr int WM = MI * 16, WN = NI * 16;
  constexpr int LIW = (IW == 8 ? 3 : (IW == 16 ? 4 : 5));
  constexpr int ICV = IC / 8;
  __shared__ bf16 Alds[PLANES * NPIX * 8];
  __shared__ bf16 Blds[2][CHUNK];

  const int tid = threadIdx.x;
  const int wave = tid >> 6, lane = tid & 63;
  const int q = lane >> 4, li = lane & 15;
  const int wm = wave / WAVES_N, wn = wave % WAVES_N;
  const int img = blockIdx.x / BPI;
  const int tb = blockIdx.x % BPI;
  const int n0 = blockIdx.y * BN;

  // ---- stage A tile: global [pix][ic] -> LDS [plane][pix][8] ----
  const bf16* src = xin + ((size_t)img * IH2 + tb * ROWS) * IW2 * IC;
  for (int g = tid; g < NPIX * ICV; g += 256) {
    const int pix = g / ICV;
    const int gr = g % ICV;
    const float4 v = *(const float4*)(src + (size_t)g * 8);
    *(float4*)(&Alds[(gr * NPIX + pix) * 8]) = v;
  }

  // ---- B prefetch: chunk -> Blds[buf] ----
  auto prefetch = [&](int chunk, int buf) {
    #pragma unroll
    for (int j = 0; j < (NP + 3) / 4; ++j) {
      const int jj = wave + 4 * j;
      if (NP % 4 != 0 && jj >= NP) break;
      size_t gelem;
      if (BN == 64) {
        gelem = ((size_t)(chunk * PLANES + jj) * OCp + n0 + lane) * 8;
      } else { // BN == 16 == OCp
        gelem = ((size_t)(chunk * PLANES + jj * 4) * OCp + lane) * 8;
      }
      gload_lds16(wt + gelem, &Blds[buf][jj * 512]);
    }
  };

  prefetch(0, 0);

  // per-mi center pixel (lane li = m-row within 16)
  int cpix[MI];
  #pragma unroll
  for (int mi = 0; mi < MI; ++mi) {
    const int m = wm * WM + mi * 16 + li;
    cpix[mi] = ((m >> LIW) + 1) * IW2 + (m & (IW - 1)) + 1;
  }

  f32x4 acc[4][MI][NI];
  #pragma unroll
  for (int p = 0; p < 4; ++p)
    #pragma unroll
    for (int mi = 0; mi < MI; ++mi)
      #pragma unroll
      for (int nj = 0; nj < NI; ++nj)
        acc[p][mi][nj] = (f32x4){0.f, 0.f, 0.f, 0.f};

  __syncthreads();

  for (int chunk = 0; chunk < 16; ++chunk) {
    if (chunk < 15) prefetch(chunk + 1, (chunk + 1) & 1);
    const int p = chunk >> 2, tap = chunk & 3;
    const int py = p >> 1, px = p & 1;
    const int sh = ((tap >> 1) ? (py ? 1 : -1) * IW2 : 0) + ((tap & 1) ? (px ? 1 : -1) : 0);
    const bf16* Bb = Blds[chunk & 1];
    #pragma unroll
    for (int c = 0; c < NC; ++c) {
      bf16x8 bfr[NI];
      #pragma unroll
      for (int nj = 0; nj < NI; ++nj)
        bfr[nj] = *(const bf16x8*)(Bb + ((c * 4 + q) * BN + wn * WN + nj * 16 + li) * 8);
      #pragma unroll
      for (int mi = 0; mi < MI; ++mi) {
        const bf16x8 a = *(const bf16x8*)(Alds + ((c * 4 + q) * NPIX + cpix[mi] + sh) * 8);
        #pragma unroll
        for (int nj = 0; nj < NI; ++nj)
          acc[p][mi][nj] = __builtin_amdgcn_mfma_f32_16x16x32_bf16(a, bfr[nj], acc[p][mi][nj], 0, 0, 0);
      }
    }
    __syncthreads();
  }

  // ---- epilogue: C/D row = q*4+r (m), col = li (oc) ----
  if (!FINAL) {
    #pragma unroll
    for (int p = 0; p < 4; ++p) {
      const int py = p >> 1, px = p & 1;
      #pragma unroll
      for (int nj = 0; nj < NI; ++nj) {
        const int oc = n0 + wn * WN + nj * 16 + li;
        const float bv = bias[oc];
        #pragma unroll
        for (int mi = 0; mi < MI; ++mi) {
          #pragma unroll
          for (int r = 0; r < 4; ++r) {
            const int pix = (wm * MI + mi) * 16 + q * 4 + r;
            const int y = tb * ROWS + (pix >> LIW), x = pix & (IW - 1);
            float v = acc[p][mi][nj][r] + bv;
            if (RELU) v = fmaxf(v, 0.f);
            xout[(((size_t)img * OH2 + 2 * y + py + 1) * OW2 + 2 * x + px + 1) * OCp + oc] =
                __float2bfloat16(v);
          }
        }
      }
    }
  } else {
    const int oc = li;  // NI==1, wn==0 for FINAL config
    if (oc < OCr) {
      const float bv = bias[oc];
      #pragma unroll
      for (int py = 0; py < 2; ++py)
        #pragma unroll
        for (int mi = 0; mi < MI; ++mi)
          #pragma unroll
          for (int r = 0; r < 4; ++r) {
            const int pix = (wm * MI + mi) * 16 + q * 4 + r;
            const int y = tb * ROWS + (pix >> LIW), x = pix & (IW - 1);
            float2 v2;
            v2.x = acc[py * 2 + 0][mi][0][r] + bv;
            v2.y = acc[py * 2 + 1][mi][0][r] + bv;
            *(float2*)(&fout[(((size_t)img * 3 + oc) * 64 + 2 * y + py) * 64 + 2 * x]) = v2;
          }
    }
  }
}

// ---------------- launch ----------------
extern "C" void kernel_launch(void* const* d_in, const int* in_sizes, int n_in,
                              void* d_out, int out_size, void* d_ws, size_t ws_size,
                              hipStream_t stream) {
  const float* x  = (const float*)d_in[0];
  const float* gw = (const float*)d_in[1];
  const float* gb = (const float*)d_in[2];
  const float* z  = (const float*)d_in[3];
  const float* w1 = (const float*)d_in[4];
  const float* b1 = (const float*)d_in[5];
  const float* w2 = (const float*)d_in[6];
  const float* b2 = (const float*)d_in[7];
  const float* w3 = (const float*)d_in[8];
  const float* b3 = (const float*)d_in[9];
  float* out = (float*)d_out;

  char* w = (char*)d_ws;
  float* lp  = (float*)(w);
  bf16* x1  = (bf16*)(w + 65536);
  bf16* x2  = (bf16*)(w + 13172736);
  bf16* x3  = (bf16*)(w + 55640064);
  bf16* wt1 = (bf16*)(w + 131399680);
  bf16* wt2 = (bf16*)(w + 131923968);
  bf16* wt3 = (bf16*)(w + 132186112);

  // halo zeroing (borders only)
  zero_halo<<<(512*36*16 + 255) / 256, 256, 0, stream>>>(x1, 8, 8, 128);
  zero_halo<<<(512*68*16 + 255) / 256, 256, 0, stream>>>(x2, 16, 16, 128);
  zero_halo<<<(512*132*8 + 255) / 256, 256, 0, stream>>>(x3, 32, 32, 64);

  // gating -> leaf probabilities
  gate_kernel<<<512, 64, 0, stream>>>(x, gw, gb, lp);

  // weight transforms (fp32 -> chunked LDS-image bf16 layout)
  wprep_kernel<<<(16*128*128 + 255) / 256, 256, 0, stream>>>(w1, wt1, 128, 128, 128);
  wprep_kernel<<<(16*64*128 + 255) / 256, 256, 0, stream>>>(w2, wt2, 128, 64, 64);
  wprep_kernel<<<(16*16*64 + 255) / 256, 256, 0, stream>>>(w3, wt3, 64, 3, 16);

  // mixture -> x1 interior (NHWC bf16)
  mixture_kernel<<<dim3(64, 8), 256, 0, stream>>>(z, lp, x1);

  // conv1: 128->128, 8x8 -> 16x16, relu. M=64/img, oc split 2. LDS 25.6+32=57.6K -> 2 blk/CU
  convt_pipe<128,128,128, 8, 8, 8, 64, 2,2, 2,2, true,false>
      <<<dim3(512, 2), 256, 0, stream>>>(x1, wt1, b1, x2, nullptr);
  // conv2: 128->64, 16x16 -> 32x32, relu. ROWS=8 -> M=128, MI=4. LDS 46.1+32=78.1K -> 2 blk/CU
  convt_pipe<128, 64, 64,16,16, 8, 64, 2,2, 4,2, true,false>
      <<<dim3(1024, 1), 256, 0, stream>>>(x2, wt2, b2, x3, nullptr);
  // conv3: 64->3(pad16), 32x32 -> 64x64, fp32 NCHW out. ROWS=8 -> M=256. LDS 43.5+4=47.5K -> 3 blk/CU
  convt_pipe< 64, 16,  3,32,32, 8, 16, 4,1, 4,1, false,true>
      <<<dim3(2048, 1), 256, 0, stream>>>(x3, wt3, b3, nullptr, out);
}